// Round 1
// baseline (23079.048 us; speedup 1.0000x reference)
//
#include <hip/hip_runtime.h>
#include <math.h>

#define BATCH 256
#define HID   512
#define DIN   256
#define SEQ   512
#define HIST  2048

__device__ __forceinline__ float sigmoidf_(float v) {
    return 1.0f / (1.0f + __expf(-v));
}

// One thread per (batch b, hidden unit u). Gate rows are wave-uniform
// (readfirstlane) so the three weight-row streams scalarize; each lane
// streams its own h/x row with float4 loads (L1-resident working set).
// Separate accumulators for r, z, n_hh, n_ih because n = tanh(i_n + r*h_n).
__global__ __launch_bounds__(512) void gru_step(
    const float* __restrict__ x_t,     // [BATCH][DIN]
    const float* __restrict__ h_prev,  // [BATCH][HID]
    const float* __restrict__ w_ih,    // [3*HID][DIN]  rows: r, z, n
    const float* __restrict__ w_hh,    // [3*HID][HID]
    float* __restrict__ h_new)         // [BATCH][HID]
{
    const int tid = threadIdx.x;
    const int b = blockIdx.x * 64 + (tid & 63);          // 4 b-tiles of 64
    int u = blockIdx.y * 8 + (tid >> 6);                 // 64 u-tiles of 8
    u = __builtin_amdgcn_readfirstlane(u);               // wave-uniform

    const float4* hr  = (const float4*)(h_prev + (size_t)b * HID);
    const float4* xr  = (const float4*)(x_t    + (size_t)b * DIN);
    const float4* wRh = (const float4*)(w_hh + (size_t)(0 * HID + u) * HID);
    const float4* wZh = (const float4*)(w_hh + (size_t)(1 * HID + u) * HID);
    const float4* wNh = (const float4*)(w_hh + (size_t)(2 * HID + u) * HID);
    const float4* wRi = (const float4*)(w_ih + (size_t)(0 * HID + u) * DIN);
    const float4* wZi = (const float4*)(w_ih + (size_t)(1 * HID + u) * DIN);
    const float4* wNi = (const float4*)(w_ih + (size_t)(2 * HID + u) * DIN);

    float aR = 0.f, aZ = 0.f, aNH = 0.f, aNI = 0.f;

    #pragma unroll 8
    for (int k = 0; k < HID / 4; ++k) {
        const float4 h4 = hr[k];
        const float4 r4 = wRh[k];
        const float4 z4 = wZh[k];
        const float4 n4 = wNh[k];
        aR  += h4.x * r4.x + h4.y * r4.y + h4.z * r4.z + h4.w * r4.w;
        aZ  += h4.x * z4.x + h4.y * z4.y + h4.z * z4.z + h4.w * z4.w;
        aNH += h4.x * n4.x + h4.y * n4.y + h4.z * n4.z + h4.w * n4.w;
    }
    #pragma unroll 8
    for (int k = 0; k < DIN / 4; ++k) {
        const float4 x4 = xr[k];
        const float4 r4 = wRi[k];
        const float4 z4 = wZi[k];
        const float4 n4 = wNi[k];
        aR  += x4.x * r4.x + x4.y * r4.y + x4.z * r4.z + x4.w * r4.w;
        aZ  += x4.x * z4.x + x4.y * z4.y + x4.z * z4.z + x4.w * z4.w;
        aNI += x4.x * n4.x + x4.y * n4.y + x4.z * n4.z + x4.w * n4.w;
    }

    const float r = sigmoidf_(aR);
    const float z = sigmoidf_(aZ);
    const float n = tanhf(aNI + r * aNH);
    const float hp = h_prev[(size_t)b * HID + u];
    h_new[(size_t)b * HID + u] = (1.0f - z) * n + z * hp;
}

// One workgroup per batch row: logits over 2048 history entries, softmax,
// mu = alpha @ external (coalesced: lane = output dim), sigma logits, and
// log_det = sum(sigma_logit) (since log|exp(l)| = l). Stores 1/sigma = exp(-l).
__global__ __launch_bounds__(256) void attn_kernel(
    const float* __restrict__ h,         // [BATCH][HID] final hidden
    const float* __restrict__ external,  // [HIST][DIN]
    const float* __restrict__ w_alpha,   // [HIST][HID]
    const float* __restrict__ w_sigma,   // [DIN][HID]
    float* __restrict__ mu,              // [BATCH][DIN]
    float* __restrict__ inv_sig,         // [BATCH][DIN]
    float* __restrict__ log_det)         // [BATCH]
{
    const int b = blockIdx.x;
    const int t = threadIdx.x;

    __shared__ float hs[HID];
    __shared__ float al[HIST];
    __shared__ float red[256];

    for (int k = t; k < HID; k += 256) hs[k] = h[(size_t)b * HID + k];
    __syncthreads();

    const float4* hs4 = (const float4*)hs;

    // logits: 8 entries per thread, e = t + 256*i
    float lg[8];
    #pragma unroll
    for (int i = 0; i < 8; ++i) {
        const int e = t + 256 * i;
        const float4* wr = (const float4*)(w_alpha + (size_t)e * HID);
        float acc = 0.f;
        #pragma unroll 4
        for (int k = 0; k < HID / 4; ++k) {
            const float4 w4 = wr[k];
            const float4 h4 = hs4[k];
            acc += w4.x * h4.x + w4.y * h4.y + w4.z * h4.z + w4.w * h4.w;
        }
        lg[i] = acc;
    }

    // block max
    float m = lg[0];
    #pragma unroll
    for (int i = 1; i < 8; ++i) m = fmaxf(m, lg[i]);
    red[t] = m;
    __syncthreads();
    for (int off = 128; off > 0; off >>= 1) {
        if (t < off) red[t] = fmaxf(red[t], red[t + off]);
        __syncthreads();
    }
    m = red[0];
    __syncthreads();

    // exp + block sum
    float s = 0.f;
    #pragma unroll
    for (int i = 0; i < 8; ++i) {
        const float v = __expf(lg[i] - m);
        al[t + 256 * i] = v;
        s += v;
    }
    red[t] = s;
    __syncthreads();
    for (int off = 128; off > 0; off >>= 1) {
        if (t < off) red[t] += red[t + off];
        __syncthreads();
    }
    s = red[0];
    const float inv_s = 1.0f / s;
    __syncthreads();

    // mu: thread t owns output dim d = t; external reads coalesced across lanes
    const int d = t;
    float acc_mu = 0.f;
    for (int e = 0; e < HIST; ++e) {
        acc_mu += al[e] * external[(size_t)e * DIN + d];
    }
    mu[(size_t)b * DIN + d] = acc_mu * inv_s;

    // sigma logit for dim d
    const float4* ws = (const float4*)(w_sigma + (size_t)d * HID);
    float sl = 0.f;
    #pragma unroll 4
    for (int k = 0; k < HID / 4; ++k) {
        const float4 w4 = ws[k];
        const float4 h4 = hs4[k];
        sl += w4.x * h4.x + w4.y * h4.y + w4.z * h4.z + w4.w * h4.w;
    }
    inv_sig[(size_t)b * DIN + d] = __expf(-sl);  // 1/sigma

    red[t] = sl;   // log|sigma| == sl
    __syncthreads();
    for (int off = 128; off > 0; off >>= 1) {
        if (t < off) red[t] += red[t + off];
        __syncthreads();
    }
    if (t == 0) log_det[b] = red[0];
}

// out[s][b] = -0.5*(maha + D*log(2pi)) - log_det[b]
__global__ __launch_bounds__(256) void out_kernel(
    const float* __restrict__ x,        // [SEQ][BATCH][DIN]
    const float* __restrict__ mu,       // [BATCH][DIN]
    const float* __restrict__ inv_sig,  // [BATCH][DIN]
    const float* __restrict__ log_det,  // [BATCH]
    float* __restrict__ out)            // [SEQ][BATCH]
{
    const int s = blockIdx.x;
    const int b = threadIdx.x;
    const float4* xr = (const float4*)(x + ((size_t)s * BATCH + b) * DIN);
    const float4* mr = (const float4*)(mu + (size_t)b * DIN);
    const float4* ir = (const float4*)(inv_sig + (size_t)b * DIN);

    float maha = 0.f;
    #pragma unroll 8
    for (int k = 0; k < DIN / 4; ++k) {
        const float4 xv = xr[k];
        const float4 mv = mr[k];
        const float4 iv = ir[k];
        const float t0 = (xv.x - mv.x) * iv.x;
        const float t1 = (xv.y - mv.y) * iv.y;
        const float t2 = (xv.z - mv.z) * iv.z;
        const float t3 = (xv.w - mv.w) * iv.w;
        maha += t0 * t0 + t1 * t1 + t2 * t2 + t3 * t3;
    }
    const float LOG2PI = 1.8378770664093453f;
    out[(size_t)s * BATCH + b] = -0.5f * (maha + (float)DIN * LOG2PI) - log_det[b];
}

extern "C" void kernel_launch(void* const* d_in, const int* in_sizes, int n_in,
                              void* d_out, int out_size, void* d_ws, size_t ws_size,
                              hipStream_t stream)
{
    const float* x        = (const float*)d_in[0];
    const float* hidden   = (const float*)d_in[1];
    const float* external = (const float*)d_in[2];
    const float* w_ih     = (const float*)d_in[3];
    const float* w_hh     = (const float*)d_in[4];
    const float* w_alpha  = (const float*)d_in[5];
    const float* w_sigma  = (const float*)d_in[6];

    // workspace layout (fp32): h ping-pong + mu + inv_sigma + log_det (~1.6 MB)
    float* h0      = (float*)d_ws;
    float* h1      = h0 + BATCH * HID;
    float* mu      = h1 + BATCH * HID;
    float* inv_sig = mu + BATCH * DIN;
    float* log_det = inv_sig + BATCH * DIN;

    hipMemcpyAsync(h0, hidden, sizeof(float) * BATCH * HID,
                   hipMemcpyDeviceToDevice, stream);

    for (int t = 0; t < SEQ; ++t) {
        const float* src = (t & 1) ? h1 : h0;
        float*       dst = (t & 1) ? h0 : h1;
        gru_step<<<dim3(4, 64), dim3(512), 0, stream>>>(
            x + (size_t)t * BATCH * DIN, src, w_ih, w_hh, dst);
    }
    // after t=511 (odd) the final hidden state is in h0

    attn_kernel<<<dim3(BATCH), dim3(256), 0, stream>>>(
        h0, external, w_alpha, w_sigma, mu, inv_sig, log_det);

    out_kernel<<<dim3(SEQ), dim3(256), 0, stream>>>(
        x, mu, inv_sig, log_det, (float*)d_out);
}

// Round 2
// 14769.035 us; speedup vs baseline: 1.5627x; 1.5627x over previous
//
#include <hip/hip_runtime.h>
#include <math.h>

#define BATCH 256
#define HID   512
#define DIN   256
#define SEQ   512
#define HIST  2048

typedef __attribute__((ext_vector_type(8))) short short8;   // 8 bf16 = 4 VGPR
typedef __attribute__((ext_vector_type(4))) float floatx4;
typedef __attribute__((ext_vector_type(8))) float floatx8;

__device__ __forceinline__ unsigned short f32_bf16_rtne(float f) {
    unsigned u = __builtin_bit_cast(unsigned, f);
    unsigned r = u + 0x7FFFu + ((u >> 16) & 1u);
    return (unsigned short)(r >> 16);
}
__device__ __forceinline__ float bf16_f32(unsigned short s) {
    unsigned u = ((unsigned)s) << 16;
    return __builtin_bit_cast(float, u);
}
__device__ __forceinline__ float sigmoidf_(float v) {
    return 1.0f / (1.0f + __expf(-v));
}

// split fp32 -> (hi, lo) bf16 pair. lo captures mantissa bits 9..16.
__global__ __launch_bounds__(256) void split_kernel(
    const float* __restrict__ src, short* __restrict__ hi, short* __restrict__ lo, int n)
{
    int i = blockIdx.x * 256 + threadIdx.x;
    if (i < n) {
        float v = src[i];
        unsigned short h = f32_bf16_rtne(v);
        hi[i] = (short)h;
        lo[i] = (short)f32_bf16_rtne(v - bf16_f32(h));
    }
}

// split + fp32 copy (for initial hidden state)
__global__ __launch_bounds__(256) void split_copy_kernel(
    const float* __restrict__ src, float* __restrict__ dst,
    short* __restrict__ hi, short* __restrict__ lo, int n)
{
    int i = blockIdx.x * 256 + threadIdx.x;
    if (i < n) {
        float v = src[i];
        dst[i] = v;
        unsigned short h = f32_bf16_rtne(v);
        hi[i] = (short)h;
        lo[i] = (short)f32_bf16_rtne(v - bf16_f32(h));
    }
}

// One GRU step via MFMA 16x16x32 bf16 with split-bf16 (hi+lo) operands.
// Grid: (BATCH/32, HID/32) blocks, 256 threads = 4 waves; wave handles a
// 16(batch) x 16(u) tile. Accumulators: aR, aZ (x+h combined), aNI (x part
// of n), aNH (h part of n) since n = tanh(i_n + r*h_n).
// Fragment layouts (guide §3, m89/m120-verified):
//   A[m=lane&15][k=quad*8+j], B(row-major [n][k]): n=lane&15, k=quad*8+j
//   D: row(m)=quad*4+reg, col(n)=lane&15
__global__ __launch_bounds__(256) void gru_step_mfma(
    const float* __restrict__ x_t,     // [BATCH][DIN] fp32
    const float* __restrict__ h_prev,  // [BATCH][HID] fp32
    const short* __restrict__ h_hi,    // [BATCH][HID] bf16 hi
    const short* __restrict__ h_lo,    // [BATCH][HID] bf16 lo
    const short* __restrict__ wih_hi,  // [3*HID][DIN]
    const short* __restrict__ wih_lo,
    const short* __restrict__ whh_hi,  // [3*HID][HID]
    const short* __restrict__ whh_lo,
    float* __restrict__ h_new,
    short* __restrict__ hn_hi,
    short* __restrict__ hn_lo)
{
    const int tid  = threadIdx.x;
    const int w    = tid >> 6;
    const int lane = tid & 63;
    const int quad = lane >> 4;
    const int n16  = lane & 15;

    const int m0 = blockIdx.x * 32 + (w & 1) * 16;   // batch tile base
    const int u0 = blockIdx.y * 32 + (w >> 1) * 16;  // hidden-unit tile base

    floatx4 aR  = {0.f, 0.f, 0.f, 0.f};
    floatx4 aZ  = {0.f, 0.f, 0.f, 0.f};
    floatx4 aNI = {0.f, 0.f, 0.f, 0.f};
    floatx4 aNH = {0.f, 0.f, 0.f, 0.f};

    const int un = u0 + n16;

    // ---------------- x part: K = DIN = 256 ----------------
    {
        const float* xp   = x_t + (m0 + n16) * DIN + quad * 8;
        const short* brH  = wih_hi + (0 * HID + un) * DIN + quad * 8;
        const short* brL  = wih_lo + (0 * HID + un) * DIN + quad * 8;
        const short* bzH  = wih_hi + (1 * HID + un) * DIN + quad * 8;
        const short* bzL  = wih_lo + (1 * HID + un) * DIN + quad * 8;
        const short* bnH  = wih_hi + (2 * HID + un) * DIN + quad * 8;
        const short* bnL  = wih_lo + (2 * HID + un) * DIN + quad * 8;

        #pragma unroll
        for (int k0 = 0; k0 < DIN; k0 += 32) {
            const floatx8 av = *(const floatx8*)(xp + k0);
            short8 ah, al;
            #pragma unroll
            for (int j = 0; j < 8; ++j) {
                const float v = av[j];
                const unsigned short hb = f32_bf16_rtne(v);
                ah[j] = (short)hb;
                al[j] = (short)f32_bf16_rtne(v - bf16_f32(hb));
            }
            const short8 rH = *(const short8*)(brH + k0);
            const short8 rL = *(const short8*)(brL + k0);
            const short8 zH = *(const short8*)(bzH + k0);
            const short8 zL = *(const short8*)(bzL + k0);
            const short8 nH = *(const short8*)(bnH + k0);
            const short8 nL = *(const short8*)(bnL + k0);

            aR  = __builtin_amdgcn_mfma_f32_16x16x32_bf16(ah, rH, aR, 0, 0, 0);
            aZ  = __builtin_amdgcn_mfma_f32_16x16x32_bf16(ah, zH, aZ, 0, 0, 0);
            aNI = __builtin_amdgcn_mfma_f32_16x16x32_bf16(ah, nH, aNI, 0, 0, 0);
            aR  = __builtin_amdgcn_mfma_f32_16x16x32_bf16(al, rH, aR, 0, 0, 0);
            aZ  = __builtin_amdgcn_mfma_f32_16x16x32_bf16(al, zH, aZ, 0, 0, 0);
            aNI = __builtin_amdgcn_mfma_f32_16x16x32_bf16(al, nH, aNI, 0, 0, 0);
            aR  = __builtin_amdgcn_mfma_f32_16x16x32_bf16(ah, rL, aR, 0, 0, 0);
            aZ  = __builtin_amdgcn_mfma_f32_16x16x32_bf16(ah, zL, aZ, 0, 0, 0);
            aNI = __builtin_amdgcn_mfma_f32_16x16x32_bf16(ah, nL, aNI, 0, 0, 0);
        }
    }

    // ---------------- h part: K = HID = 512 ----------------
    {
        const short* hH   = h_hi + (m0 + n16) * HID + quad * 8;
        const short* hL   = h_lo + (m0 + n16) * HID + quad * 8;
        const short* brH  = whh_hi + (0 * HID + un) * HID + quad * 8;
        const short* brL  = whh_lo + (0 * HID + un) * HID + quad * 8;
        const short* bzH  = whh_hi + (1 * HID + un) * HID + quad * 8;
        const short* bzL  = whh_lo + (1 * HID + un) * HID + quad * 8;
        const short* bnH  = whh_hi + (2 * HID + un) * HID + quad * 8;
        const short* bnL  = whh_lo + (2 * HID + un) * HID + quad * 8;

        #pragma unroll 4
        for (int k0 = 0; k0 < HID; k0 += 32) {
            const short8 ah = *(const short8*)(hH + k0);
            const short8 al = *(const short8*)(hL + k0);
            const short8 rH = *(const short8*)(brH + k0);
            const short8 rL = *(const short8*)(brL + k0);
            const short8 zH = *(const short8*)(bzH + k0);
            const short8 zL = *(const short8*)(bzL + k0);
            const short8 nH = *(const short8*)(bnH + k0);
            const short8 nL = *(const short8*)(bnL + k0);

            aR  = __builtin_amdgcn_mfma_f32_16x16x32_bf16(ah, rH, aR, 0, 0, 0);
            aZ  = __builtin_amdgcn_mfma_f32_16x16x32_bf16(ah, zH, aZ, 0, 0, 0);
            aNH = __builtin_amdgcn_mfma_f32_16x16x32_bf16(ah, nH, aNH, 0, 0, 0);
            aR  = __builtin_amdgcn_mfma_f32_16x16x32_bf16(al, rH, aR, 0, 0, 0);
            aZ  = __builtin_amdgcn_mfma_f32_16x16x32_bf16(al, zH, aZ, 0, 0, 0);
            aNH = __builtin_amdgcn_mfma_f32_16x16x32_bf16(al, nH, aNH, 0, 0, 0);
            aR  = __builtin_amdgcn_mfma_f32_16x16x32_bf16(ah, rL, aR, 0, 0, 0);
            aZ  = __builtin_amdgcn_mfma_f32_16x16x32_bf16(ah, zL, aZ, 0, 0, 0);
            aNH = __builtin_amdgcn_mfma_f32_16x16x32_bf16(ah, nL, aNH, 0, 0, 0);
        }
    }

    // ---------------- epilogue: gates + h update ----------------
    #pragma unroll
    for (int rr = 0; rr < 4; ++rr) {
        const int b = m0 + quad * 4 + rr;
        const float r = sigmoidf_(aR[rr]);
        const float z = sigmoidf_(aZ[rr]);
        const float n = tanhf(aNI[rr] + r * aNH[rr]);
        const float hp = h_prev[b * HID + un];
        const float hn = (1.0f - z) * n + z * hp;
        h_new[b * HID + un] = hn;
        const unsigned short hb = f32_bf16_rtne(hn);
        hn_hi[b * HID + un] = (short)hb;
        hn_lo[b * HID + un] = (short)f32_bf16_rtne(hn - bf16_f32(hb));
    }
}

// --- attention / sigma / mu (fp32, unchanged from R1) ---
__global__ __launch_bounds__(256) void attn_kernel(
    const float* __restrict__ h,
    const float* __restrict__ external,
    const float* __restrict__ w_alpha,
    const float* __restrict__ w_sigma,
    float* __restrict__ mu,
    float* __restrict__ inv_sig,
    float* __restrict__ log_det)
{
    const int b = blockIdx.x;
    const int t = threadIdx.x;

    __shared__ float hs[HID];
    __shared__ float al[HIST];
    __shared__ float red[256];

    for (int k = t; k < HID; k += 256) hs[k] = h[(size_t)b * HID + k];
    __syncthreads();

    const float4* hs4 = (const float4*)hs;

    float lg[8];
    #pragma unroll
    for (int i = 0; i < 8; ++i) {
        const int e = t + 256 * i;
        const float4* wr = (const float4*)(w_alpha + (size_t)e * HID);
        float acc = 0.f;
        #pragma unroll 4
        for (int k = 0; k < HID / 4; ++k) {
            const float4 w4 = wr[k];
            const float4 h4 = hs4[k];
            acc += w4.x * h4.x + w4.y * h4.y + w4.z * h4.z + w4.w * h4.w;
        }
        lg[i] = acc;
    }

    float m = lg[0];
    #pragma unroll
    for (int i = 1; i < 8; ++i) m = fmaxf(m, lg[i]);
    red[t] = m;
    __syncthreads();
    for (int off = 128; off > 0; off >>= 1) {
        if (t < off) red[t] = fmaxf(red[t], red[t + off]);
        __syncthreads();
    }
    m = red[0];
    __syncthreads();

    float s = 0.f;
    #pragma unroll
    for (int i = 0; i < 8; ++i) {
        const float v = __expf(lg[i] - m);
        al[t + 256 * i] = v;
        s += v;
    }
    red[t] = s;
    __syncthreads();
    for (int off = 128; off > 0; off >>= 1) {
        if (t < off) red[t] += red[t + off];
        __syncthreads();
    }
    s = red[0];
    const float inv_s = 1.0f / s;
    __syncthreads();

    const int d = t;
    float acc_mu = 0.f;
    for (int e = 0; e < HIST; ++e) {
        acc_mu += al[e] * external[(size_t)e * DIN + d];
    }
    mu[(size_t)b * DIN + d] = acc_mu * inv_s;

    const float4* ws = (const float4*)(w_sigma + (size_t)d * HID);
    float sl = 0.f;
    #pragma unroll 4
    for (int k = 0; k < HID / 4; ++k) {
        const float4 w4 = ws[k];
        const float4 h4 = hs4[k];
        sl += w4.x * h4.x + w4.y * h4.y + w4.z * h4.z + w4.w * h4.w;
    }
    inv_sig[(size_t)b * DIN + d] = __expf(-sl);

    red[t] = sl;
    __syncthreads();
    for (int off = 128; off > 0; off >>= 1) {
        if (t < off) red[t] += red[t + off];
        __syncthreads();
    }
    if (t == 0) log_det[b] = red[0];
}

__global__ __launch_bounds__(256) void out_kernel(
    const float* __restrict__ x,
    const float* __restrict__ mu,
    const float* __restrict__ inv_sig,
    const float* __restrict__ log_det,
    float* __restrict__ out)
{
    const int s = blockIdx.x;
    const int b = threadIdx.x;
    const float4* xr = (const float4*)(x + ((size_t)s * BATCH + b) * DIN);
    const float4* mr = (const float4*)(mu + (size_t)b * DIN);
    const float4* ir = (const float4*)(inv_sig + (size_t)b * DIN);

    float maha = 0.f;
    #pragma unroll 8
    for (int k = 0; k < DIN / 4; ++k) {
        const float4 xv = xr[k];
        const float4 mv = mr[k];
        const float4 iv = ir[k];
        const float t0 = (xv.x - mv.x) * iv.x;
        const float t1 = (xv.y - mv.y) * iv.y;
        const float t2 = (xv.z - mv.z) * iv.z;
        const float t3 = (xv.w - mv.w) * iv.w;
        maha += t0 * t0 + t1 * t1 + t2 * t2 + t3 * t3;
    }
    const float LOG2PI = 1.8378770664093453f;
    out[(size_t)s * BATCH + b] = -0.5f * (maha + (float)DIN * LOG2PI) - log_det[b];
}

extern "C" void kernel_launch(void* const* d_in, const int* in_sizes, int n_in,
                              void* d_out, int out_size, void* d_ws, size_t ws_size,
                              hipStream_t stream)
{
    const float* x        = (const float*)d_in[0];
    const float* hidden   = (const float*)d_in[1];
    const float* external = (const float*)d_in[2];
    const float* w_ih     = (const float*)d_in[3];
    const float* w_hh     = (const float*)d_in[4];
    const float* w_alpha  = (const float*)d_in[5];
    const float* w_sigma  = (const float*)d_in[6];

    const int NH  = BATCH * HID;      // 131072
    const int NIH = 3 * HID * DIN;    // 393216
    const int NHH = 3 * HID * HID;    // 786432

    // ws layout (all 16B-aligned: sizes are multiples of 16B)
    char* p = (char*)d_ws;
    float* h0      = (float*)p; p += NH * 4;
    float* h1      = (float*)p; p += NH * 4;
    short* hhi0    = (short*)p; p += NH * 2;
    short* hlo0    = (short*)p; p += NH * 2;
    short* hhi1    = (short*)p; p += NH * 2;
    short* hlo1    = (short*)p; p += NH * 2;
    short* wih_hi  = (short*)p; p += NIH * 2;
    short* wih_lo  = (short*)p; p += NIH * 2;
    short* whh_hi  = (short*)p; p += NHH * 2;
    short* whh_lo  = (short*)p; p += NHH * 2;
    float* mu      = (float*)p; p += BATCH * DIN * 4;
    float* inv_sig = (float*)p; p += BATCH * DIN * 4;
    float* log_det = (float*)p; p += BATCH * 4;

    split_kernel<<<(NIH + 255) / 256, 256, 0, stream>>>(w_ih, wih_hi, wih_lo, NIH);
    split_kernel<<<(NHH + 255) / 256, 256, 0, stream>>>(w_hh, whh_hi, whh_lo, NHH);
    split_copy_kernel<<<(NH + 255) / 256, 256, 0, stream>>>(hidden, h0, hhi0, hlo0, NH);

    for (int t = 0; t < SEQ; ++t) {
        const int even = ((t & 1) == 0);
        const float* hsrc = even ? h0 : h1;
        float*       hdst = even ? h1 : h0;
        const short* shi  = even ? hhi0 : hhi1;
        const short* slo  = even ? hlo0 : hlo1;
        short*       dhi  = even ? hhi1 : hhi0;
        short*       dlo  = even ? hlo1 : hlo0;
        gru_step_mfma<<<dim3(BATCH / 32, HID / 32), dim3(256), 0, stream>>>(
            x + (size_t)t * BATCH * DIN, hsrc, shi, slo,
            wih_hi, wih_lo, whh_hi, whh_lo, hdst, dhi, dlo);
    }
    // SEQ=512 even -> final hidden state in h0

    attn_kernel<<<dim3(BATCH), dim3(256), 0, stream>>>(
        h0, external, w_alpha, w_sigma, mu, inv_sig, log_det);

    out_kernel<<<dim3(SEQ), dim3(256), 0, stream>>>(
        x, mu, inv_sig, log_det, (float*)d_out);
}